// Round 11
// baseline (245.074 us; speedup 1.0000x reference)
//
#include <hip/hip_runtime.h>
#include <math.h>

#define EPS_YAT (1.0f/137.0f)

typedef unsigned short u16;
typedef unsigned int u32;
typedef __attribute__((ext_vector_type(8))) __bf16 bf16x8;
typedef __attribute__((ext_vector_type(4))) float f32x4;

__device__ __forceinline__ float4 ld4(const float* p) { return *(const float4*)p; }

__device__ __forceinline__ u16 bf16_rne(float f) {
    u32 u = __float_as_uint(f);
    u32 r = (u + 0x7fffu + ((u >> 16) & 1u)) >> 16;
    return (u16)r;
}
__device__ __forceinline__ float bf16_f(u16 h) {
    return __uint_as_float(((u32)h) << 16);
}

// async global->LDS DMA, 16B per lane. LDS dest is wave-uniform base + lane*16
// (m104); global src is per-lane (m173) -> swizzles go on the SOURCE address.
__device__ __forceinline__ void glds16(const u16* g, u16* s) {
    __builtin_amdgcn_global_load_lds(
        (const __attribute__((address_space(1))) void*)g,
        (__attribute__((address_space(3))) void*)s,
        16, 0, 0);
}

// ---- merged column-norm partials for BOTH weight matrices (K=768) ----
__global__ void colnorm_part2(const float* __restrict__ Wa, const float* __restrict__ Wp,
                              float* __restrict__ pa, float* __restrict__ pp) {
    __shared__ float sm[256];
    const float* W; float* part; int N, colbase;
    if (blockIdx.x < 36) { W = Wa; part = pa; N = 2304; colbase = blockIdx.x * 64; }
    else                 { W = Wp; part = pp; N = 768;  colbase = (blockIdx.x - 36) * 64; }
    const int col = colbase + (threadIdx.x & 63);
    const int q = threadIdx.x >> 6;
    const int k0 = blockIdx.y * 48 + q * 12;
    float s = 0.f;
    for (int k = k0; k < k0 + 12; ++k) {
        float w = W[(size_t)k * N + col];
        s += w * w;
    }
    sm[threadIdx.x] = s;
    __syncthreads();
    if (threadIdx.x < 64)
        part[(size_t)blockIdx.y * N + col] =
            sm[threadIdx.x] + sm[threadIdx.x + 64] + sm[threadIdx.x + 128] + sm[threadIdx.x + 192];
}

// merged reduce for both matrices + zero the an accumulator (flash atomics)
__global__ void colnorm_reduce2(const float* __restrict__ pa, const float* __restrict__ pp,
                                float* __restrict__ wa, float* __restrict__ wp,
                                float* __restrict__ an_zero) {
    int gid = blockIdx.x * 256 + threadIdx.x;
    if (gid < 2304) {
        float s = 0.f;
        #pragma unroll
        for (int i = 0; i < 16; ++i) s += pa[(size_t)i * 2304 + gid];
        wa[gid] = s;
    } else if (gid < 3072) {
        int g = gid - 2304;
        float s = 0.f;
        #pragma unroll
        for (int i = 0; i < 16; ++i) s += pp[(size_t)i * 768 + g];
        wp[g] = s;
    }
    int z = gid - 3072;
    if (z >= 0 && z < 4096) an_zero[z] = 0.f;
}

// ---- fused bf16 double-split + row norms of x (K=768): one read pass ----
__global__ void split_rownorm(const float* __restrict__ X, u16* __restrict__ Xh,
                              u16* __restrict__ Xl, float* __restrict__ rn) {
    int wave = threadIdx.x >> 6;
    int lane = threadIdx.x & 63;
    int row = blockIdx.x * 4 + wave;
    const float* xr = X + (size_t)row * 768;
    u16* xh = Xh + (size_t)row * 768;
    u16* xl = Xl + (size_t)row * 768;
    float s = 0.f;
    #pragma unroll
    for (int k = lane * 4; k < 768; k += 256) {
        float4 v = ld4(xr + k);
        s += v.x * v.x + v.y * v.y + v.z * v.z + v.w * v.w;
        u16 h0 = bf16_rne(v.x), h1 = bf16_rne(v.y), h2 = bf16_rne(v.z), h3 = bf16_rne(v.w);
        u16 l0 = bf16_rne(v.x - bf16_f(h0));
        u16 l1 = bf16_rne(v.y - bf16_f(h1));
        u16 l2 = bf16_rne(v.z - bf16_f(h2));
        u16 l3 = bf16_rne(v.w - bf16_f(h3));
        uint2 hp, lp;
        hp.x = (u32)h0 | ((u32)h1 << 16); hp.y = (u32)h2 | ((u32)h3 << 16);
        lp.x = (u32)l0 | ((u32)l1 << 16); lp.y = (u32)l2 | ((u32)l3 << 16);
        *(uint2*)(xh + k) = hp;
        *(uint2*)(xl + k) = lp;
    }
    for (int off = 32; off; off >>= 1) s += __shfl_down(s, off);
    if (lane == 0) rn[row] = s;
}

// ---- transpose + bf16 double-split: W [K][N] -> Th, Tl [N][K] ----
__global__ void split_wt_kernel(const float* __restrict__ W, u16* __restrict__ Th,
                                u16* __restrict__ Tl, int K, int N) {
    __shared__ float tile[64 * 68];
    const int tid = threadIdx.x;
    const int n0 = blockIdx.x << 6;
    const int k0 = blockIdx.y << 6;
    const int rr = tid >> 4;
    const int cc = (tid & 15) << 2;
    #pragma unroll
    for (int s = 0; s < 4; ++s) {
        int k_l = rr + s * 16;
        *(float4*)&tile[k_l * 68 + cc] = ld4(W + (size_t)(k0 + k_l) * N + n0 + cc);
    }
    __syncthreads();
    #pragma unroll
    for (int s = 0; s < 4; ++s) {
        int n_l = rr + s * 16;
        float a0 = tile[(cc + 0) * 68 + n_l];
        float a1 = tile[(cc + 1) * 68 + n_l];
        float a2 = tile[(cc + 2) * 68 + n_l];
        float a3 = tile[(cc + 3) * 68 + n_l];
        u16 h0 = bf16_rne(a0), h1 = bf16_rne(a1), h2 = bf16_rne(a2), h3 = bf16_rne(a3);
        u16 l0 = bf16_rne(a0 - bf16_f(h0));
        u16 l1 = bf16_rne(a1 - bf16_f(h1));
        u16 l2 = bf16_rne(a2 - bf16_f(h2));
        u16 l3 = bf16_rne(a3 - bf16_f(h3));
        uint2 hp, lp;
        hp.x = (u32)h0 | ((u32)h1 << 16); hp.y = (u32)h2 | ((u32)h3 << 16);
        lp.x = (u32)l0 | ((u32)l1 << 16); lp.y = (u32)l2 | ((u32)l3 << 16);
        size_t o = (size_t)(n0 + n_l) * K + k0 + cc;
        *(uint2*)(Th + o) = hp;
        *(uint2*)(Tl + o) = lp;
    }
}

// ---- yat GEMM, T4 counted-vmcnt pipeline (m218: counted-vs-drain0 +38-73%).
// Double-buffered LDS, BK=32. Per iter: s_barrier (prev reads done) ->
// STAGE(next buf) -> s_waitcnt vmcnt(NLOADS) [waits ONLY current tile's DMAs;
// next tile's stay in flight under the MFMAs] -> s_barrier -> compute.
// Count trace: prologue 8 out; iter: +8 -> vmcnt(8) drains exactly the
// current tile; every wave passes its wait before the barrier => tile staged.
// Chunk-XOR source swizzle retained (rule #21 both-sides involution).
template<int SPLIT, int BIG>
__global__ __launch_bounds__(256, BIG ? 2 : 4)
void yat_gemm_mfma(const u16* __restrict__ Ah, const u16* __restrict__ Al,
                   const u16* __restrict__ Bh, const u16* __restrict__ Bl,
                   const float* __restrict__ bias, const float* __restrict__ xn,
                   const float* __restrict__ wnc, const float* __restrict__ alphap,
                   const float Fdim, float* __restrict__ out,
                   u16* __restrict__ outh, u16* __restrict__ outl,
                   float* __restrict__ qn, float* __restrict__ kn,
                   const int N, const int K) {
    constexpr int TM = BIG ? 128 : 64;
    constexpr int TN = BIG ? 128 : 64;
    constexpr int JN = BIG ? 4 : 1;       // wave's n-subtiles (16 cols each)
    constexpr int ASZ = TM * 32;          // u16 per A array per buffer
    constexpr int BSZ = TN * 32;
    constexpr int BUF = 2 * ASZ + 2 * BSZ;
    __shared__ __align__(16) u16 lds[2 * BUF];
    const int tid = threadIdx.x;
    // XCD swizzle (bijective: nwg 576 / 768, both %8==0)
    const int nwg = gridDim.x * gridDim.y;
    const int orig = blockIdx.y * gridDim.x + blockIdx.x;
    const int swz = (orig & 7) * (nwg >> 3) + (orig >> 3);
    const int m0 = (swz / gridDim.x) * TM;
    const int n0 = (swz % gridDim.x) * TN;
    const int w = tid >> 6;
    const int l = tid & 63;
    const int lm = l & 15;
    const int kq = l >> 4;
    const int kq4 = kq << 2;
    const int WM = BIG ? ((w >> 1) << 6) : 0;
    const int WN = BIG ? ((w & 1) << 6) : (w << 4);

    // staging: one glds16 line = 4 waves x 16 rows x 64B. lane l -> row +(l>>2),
    // global 16B chunk (l&3)^((l>>2)&3)  [involution within each 4-row stripe]
    const int lrow = l >> 2;
    const int swch = ((l & 3) ^ (lrow & 3)) << 3;

    f32x4 acc[4][JN] = {};

    #define STAGE(bufp, kk) { \
        u16* sb = lds + (bufp) * BUF; \
        _Pragma("unroll") \
        for (int c = 0; c < TM / 64; ++c) { \
            const int rg = 16 * (4 * c + w); \
            const size_t go = (size_t)(m0 + rg + lrow) * K + (kk) + swch; \
            glds16(Ah + go, sb + rg * 32); \
            glds16(Al + go, sb + ASZ + rg * 32); \
        } \
        _Pragma("unroll") \
        for (int c = 0; c < TN / 64; ++c) { \
            const int rg = 16 * (4 * c + w); \
            const size_t go = (size_t)(n0 + rg + lrow) * K + (kk) + swch; \
            glds16(Bh + go, sb + 2 * ASZ + rg * 32); \
            glds16(Bl + go, sb + 2 * ASZ + BSZ + rg * 32); \
        } }

    STAGE(0, 0);
    int cur = 0;
    for (int k0 = 0; k0 < K; k0 += 32) {
        __builtin_amdgcn_s_barrier();       // prev iter's frag reads done
        if (k0 + 32 < K) {
            STAGE(cur ^ 1, k0 + 32);
            if constexpr (BIG) asm volatile("s_waitcnt vmcnt(8)" ::: "memory");
            else               asm volatile("s_waitcnt vmcnt(4)" ::: "memory");
        } else {
            asm volatile("s_waitcnt vmcnt(0)" ::: "memory");
        }
        __builtin_amdgcn_sched_barrier(0);
        __builtin_amdgcn_s_barrier();       // all waves' current-tile DMAs landed

        const u16* sb  = lds + cur * BUF;
        const u16* sAh = sb;
        const u16* sAl = sb + ASZ;
        const u16* sBh = sb + 2 * ASZ;
        const u16* sBl = sb + 2 * ASZ + BSZ;
        const int ch = ((kq ^ (lm & 3)) << 3);   // swizzled read chunk
        bf16x8 fah[4], fal[4], fbh[JN], fbl[JN];
        #pragma unroll
        for (int i = 0; i < 4; ++i) {
            const int ra = (WM + i * 16 + lm) * 32 + ch;
            fah[i] = *(const bf16x8*)&sAh[ra];
            fal[i] = *(const bf16x8*)&sAl[ra];
        }
        #pragma unroll
        for (int j = 0; j < JN; ++j) {
            const int rb = (WN + j * 16 + lm) * 32 + ch;
            fbh[j] = *(const bf16x8*)&sBh[rb];
            fbl[j] = *(const bf16x8*)&sBl[rb];
        }
        #pragma unroll
        for (int i = 0; i < 4; ++i)
            #pragma unroll
            for (int j = 0; j < JN; ++j) {
                f32x4 c = acc[i][j];
                c = __builtin_amdgcn_mfma_f32_16x16x32_bf16(fah[i], fbh[j], c, 0, 0, 0);
                c = __builtin_amdgcn_mfma_f32_16x16x32_bf16(fah[i], fbl[j], c, 0, 0, 0);
                c = __builtin_amdgcn_mfma_f32_16x16x32_bf16(fal[i], fbh[j], c, 0, 0, 0);
                acc[i][j] = c;
            }
        cur ^= 1;
    }
    #undef STAGE

    const float scale = powf(sqrtf(Fdim) / log1pf(Fdim), *alphap);
    float pp[4][4];
    #pragma unroll
    for (int i = 0; i < 4; ++i) {
        const int mbase = m0 + WM + i * 16 + kq4;
        #pragma unroll
        for (int r = 0; r < 4; ++r) pp[i][r] = 0.f;
        #pragma unroll
        for (int j = 0; j < JN; ++j) {
            const int n = n0 + WN + j * 16 + lm;
            const float w2 = wnc[n];
            const float bv = bias[n];
            #pragma unroll
            for (int r = 0; r < 4; ++r) {
                const int m = mbase + r;
                float d = acc[i][j][r];
                float den = xn[m] + w2 - 2.f * d + EPS_YAT;
                float v = (d * d / den + bv) * scale;
                if constexpr (SPLIT) {
                    u16 hh = bf16_rne(v);
                    outh[(size_t)m * N + n] = hh;
                    outl[(size_t)m * N + n] = bf16_rne(v - bf16_f(hh));
                    pp[i][r] += v * v;
                } else {
                    out[(size_t)m * N + n] = v;
                }
            }
        }
    }

    if constexpr (SPLIT) {
        // fused q/k norms: wave quadrant = one head's 64 cols x 64 rows.
        const int hcol = n0 + WN;
        if (hcol < 1536) {
            #pragma unroll
            for (int i = 0; i < 4; ++i)
                #pragma unroll
                for (int r = 0; r < 4; ++r) {
                    float s = pp[i][r];
                    s += __shfl_xor(s, 1, 16);
                    s += __shfl_xor(s, 2, 16);
                    s += __shfl_xor(s, 4, 16);
                    s += __shfl_xor(s, 8, 16);
                    if (lm == 0) {
                        const int m = m0 + WM + i * 16 + kq4 + r;
                        const int bb = m >> 10, t = m & 1023;
                        if (hcol < 768)
                            qn[(bb * 12 + (hcol >> 6)) * 1024 + t] = s;
                        else
                            kn[(bb * 12 + ((hcol - 768) >> 6)) * 1024 + t] = s;
                    }
                }
        }
    }
}

// ======================= MFMA flash attention (yat score) ====================
// (256,2): (256,4) capped VGPR at 64 and spilled (R5 lesson). T13 defer-max +
// fused an row-norm (atomicAdd per wave-row).
#define MFMA_B16(a, b, c) __builtin_amdgcn_mfma_f32_16x16x32_bf16(a, b, c, 0, 0, 0)

#define ST_TILE(j) { \
    const int kro = ((j)*16 + lm) * 72 + (kq << 3); \
    bf16x8 kh = *(const bf16x8*)&KPh[kro]; \
    bf16x8 kl = *(const bf16x8*)&KPl[kro]; \
    st##j = MFMA_B16(kh, qh0, st##j); \
    st##j = MFMA_B16(kl, qh0, st##j); \
    st##j = MFMA_B16(kh, ql0, st##j); \
    kh = *(const bf16x8*)&KPh[kro + 32]; \
    kl = *(const bf16x8*)&KPl[kro + 32]; \
    st##j = MFMA_B16(kh, qh1, st##j); \
    st##j = MFMA_B16(kl, qh1, st##j); \
    st##j = MFMA_B16(kh, ql1, st##j); \
}

#define YAT_EL(j, r) { \
    float sv = st##j[r] * 0.125f; \
    float den = qnm + kns[(j)*16 + kq4 + (r)] - 2.f * sv + EPS_YAT; \
    float v = sv * sv / den; \
    if (diag && ((j)*16 + kq4 + (r) > wband + lm)) v = -3e38f; \
    st##j[r] = v; mm = fmaxf(mm, v); }
#define YAT_TILE(j) YAT_EL(j,0) YAT_EL(j,1) YAT_EL(j,2) YAT_EL(j,3)

#define PEXP_TILE(j) { \
    float p0 = __expf(st##j[0] - mnew), p1 = __expf(st##j[1] - mnew); \
    float p2 = __expf(st##j[2] - mnew), p3 = __expf(st##j[3] - mnew); \
    rs += p0 + p1 + p2 + p3; \
    u16 h0 = bf16_rne(p0), h1 = bf16_rne(p1), h2 = bf16_rne(p2), h3 = bf16_rne(p3); \
    uint2 hp; hp.x = (u32)h0 | ((u32)h1 << 16); hp.y = (u32)h2 | ((u32)h3 << 16); \
    *(uint2*)&KPh[pmrow + (j)*16 + kq4] = hp; \
    u16 e0 = bf16_rne(p0 - bf16_f(h0)), e1 = bf16_rne(p1 - bf16_f(h1)); \
    u16 e2 = bf16_rne(p2 - bf16_f(h2)), e3 = bf16_rne(p3 - bf16_f(h3)); \
    uint2 lp; lp.x = (u32)e0 | ((u32)e1 << 16); lp.y = (u32)e2 | ((u32)e3 << 16); \
    *(uint2*)&KPl[pmrow + (j)*16 + kq4] = lp; }

#define PV_TILE(j) { \
    const int vro = ((j)*16 + lm) * 72 + vkq8; \
    bf16x8 vh = *(const bf16x8*)&Vth[vro]; \
    bf16x8 vl = *(const bf16x8*)&Vtl[vro]; \
    ac##j = MFMA_B16(ph0, vh, ac##j); \
    ac##j = MFMA_B16(pl0, vh, ac##j); \
    ac##j = MFMA_B16(ph0, vl, ac##j); \
    vh = *(const bf16x8*)&Vth[vro + 32]; \
    vl = *(const bf16x8*)&Vtl[vro + 32]; \
    ac##j = MFMA_B16(ph1, vh, ac##j); \
    ac##j = MFMA_B16(pl1, vh, ac##j); \
    ac##j = MFMA_B16(ph1, vl, ac##j); \
}

// transposed V staging from a pre-split uint2 (4 u16 along d), token column toks
#define WRVT(dst, v2, m) { \
    dst[(sj * 4 + 16 * (m) + 0) * 72 + toks] = (u16)((v2).x); \
    dst[(sj * 4 + 16 * (m) + 1) * 72 + toks] = (u16)((v2).x >> 16); \
    dst[(sj * 4 + 16 * (m) + 2) * 72 + toks] = (u16)((v2).y); \
    dst[(sj * 4 + 16 * (m) + 3) * 72 + toks] = (u16)((v2).y >> 16); }

__global__ __launch_bounds__(256, 2)
void yat_flash_mfma(const u16* __restrict__ qh_g, const u16* __restrict__ ql_g,
                    const float* __restrict__ qn, const float* __restrict__ kn,
                    u16* __restrict__ outh, u16* __restrict__ outl,
                    float* __restrict__ an_g) {
    __shared__ __align__(16) u16 KPh[64 * 72], KPl[64 * 72];  // Q prologue; K; P after St
    __shared__ __align__(16) u16 Vth[64 * 72], Vtl[64 * 72];  // V^T [d][tok^swz]
    __shared__ float kns[64];

    const int tid = threadIdx.x;
    const int L = blockIdx.x;         // 0..767
    const int u = L / 48;
    const int qt = (u & 1) ? (u >> 1) : (15 - (u >> 1));
    const int bh = L % 48;
    const int h = bh % 12, b = bh / 12;
    const int wave = tid >> 6;
    const int lane = tid & 63;
    const int lm = lane & 15;
    const int kq = lane >> 4;
    const int kq4 = kq << 2;
    const int wband = wave << 4;
    const int sr = tid >> 2;          // staging token row 0..63
    const int sj = tid & 3;           // staging d-group
    const int toks = sr ^ (sj << 3);  // swizzled Vt column
    const int vkq8 = (kq ^ (lm >> 2)) << 3;
    const size_t base = (size_t)(b * 1024) * 2304 + h * 64;

    // ---- stage Q through KPh/KPl (only needed until frag reads) ----
    {
        const size_t qoff = base + (size_t)((qt << 6) + sr) * 2304 + sj * 16;
        *(uint4*)&KPh[sr * 72 + sj * 16]     = *(const uint4*)(qh_g + qoff);
        *(uint4*)&KPh[sr * 72 + sj * 16 + 8] = *(const uint4*)(qh_g + qoff + 8);
        *(uint4*)&KPl[sr * 72 + sj * 16]     = *(const uint4*)(ql_g + qoff);
        *(uint4*)&KPl[sr * 72 + sj * 16 + 8] = *(const uint4*)(ql_g + qoff + 8);
    }
    const float qnm = qn[bh * 1024 + (qt << 6) + wband + lm];

    // prefetch kt=0 K/V (pre-split u16) into registers
    const size_t r0 = base + (size_t)sr * 2304;
    uint4 kh0 = *(const uint4*)(qh_g + r0 + 768 + sj * 16);
    uint4 kh1 = *(const uint4*)(qh_g + r0 + 768 + sj * 16 + 8);
    uint4 kl0 = *(const uint4*)(ql_g + r0 + 768 + sj * 16);
    uint4 kl1 = *(const uint4*)(ql_g + r0 + 768 + sj * 16 + 8);
    uint2 vh0 = *(const uint2*)(qh_g + r0 + 1536 + sj * 4);
    uint2 vh1 = *(const uint2*)(qh_g + r0 + 1536 + sj * 4 + 16);
    uint2 vh2 = *(const uint2*)(qh_g + r0 + 1536 + sj * 4 + 32);
    uint2 vh3 = *(const uint2*)(qh_g + r0 + 1536 + sj * 4 + 48);
    uint2 vl0 = *(const uint2*)(ql_g + r0 + 1536 + sj * 4);
    uint2 vl1 = *(const uint2*)(ql_g + r0 + 1536 + sj * 4 + 16);
    uint2 vl2 = *(const uint2*)(ql_g + r0 + 1536 + sj * 4 + 32);
    uint2 vl3 = *(const uint2*)(ql_g + r0 + 1536 + sj * 4 + 48);
    float knS = (tid < 64) ? kn[bh * 1024 + tid] : 0.f;

    __syncthreads();  // Q staged

    // loop-invariant Q fragments (B-operand: Q^T via row-major Q)
    const int qrow = (wband + lm) * 72;
    const bf16x8 qh0 = *(const bf16x8*)&KPh[qrow + (kq << 3)];
    const bf16x8 qh1 = *(const bf16x8*)&KPh[qrow + 32 + (kq << 3)];
    const bf16x8 ql0 = *(const bf16x8*)&KPl[qrow + (kq << 3)];
    const bf16x8 ql1 = *(const bf16x8*)&KPl[qrow + 32 + (kq << 3)];

    f32x4 ac0 = {}, ac1 = {}, ac2 = {}, ac3 = {};
    float mrun = -3e38f, lrun = 0.f;
    const int pmrow = (wband + lm) * 72;

    for (int kt = 0; kt <= qt; ++kt) {
        __syncthreads();  // Q frag reads (iter0) / prior PV reads done
        *(uint4*)&KPh[sr * 72 + sj * 16]     = kh0;
        *(uint4*)&KPh[sr * 72 + sj * 16 + 8] = kh1;
        *(uint4*)&KPl[sr * 72 + sj * 16]     = kl0;
        *(uint4*)&KPl[sr * 72 + sj * 16 + 8] = kl1;
        WRVT(Vth, vh0, 0) WRVT(Vth, vh1, 1) WRVT(Vth, vh2, 2) WRVT(Vth, vh3, 3)
        WRVT(Vtl, vl0, 0) WRVT(Vtl, vl1, 1) WRVT(Vtl, vl2, 2) WRVT(Vtl, vl3, 3)
        if (tid < 64) kns[tid] = knS;
        __syncthreads();

        if (kt < qt) {  // prefetch kt+1 (block-uniform)
            const size_t r = base + (size_t)(((kt + 1) << 6) + sr) * 2304;
            kh0 = *(const uint4*)(qh_g + r + 768 + sj * 16);
            kh1 = *(const uint4*)(qh_g + r + 768 + sj * 16 + 8);
            kl0 = *(const uint4*)(ql_g + r + 768 + sj * 16);
            kl1 = *(const uint4*)(ql_g + r + 768 + sj * 16 + 8);
            vh0 = *(const uint2*)(qh_g + r + 1536 + sj * 4);
            vh1 = *(const uint2*)(qh_g + r + 1536 + sj * 4 + 16);
            vh2 = *(const uint2*)(qh_g + r + 1536 + sj * 4 + 32);
            vh3 = *(const uint2*)(qh_g + r + 1536 + sj * 4 + 48);
            vl0 = *(const uint2*)(ql_g + r + 1536 + sj * 4);
            vl1 = *(const uint2*)(ql_g + r + 1536 + sj * 4 + 16);
            vl2 = *(const uint2*)(ql_g + r + 1536 + sj * 4 + 32);
            vl3 = *(const uint2*)(ql_g + r + 1536 + sj * 4 + 48);
            if (tid < 64) knS = kn[bh * 1024 + ((kt + 1) << 6) + tid];
        }

        // ---- St = K.Q^T (each lane: one m = wband+lm, n = j*16+kq*4+r) ----
        f32x4 st0 = {}, st1 = {}, st2 = {}, st3 = {};
        __builtin_amdgcn_s_setprio(1);
        ST_TILE(0) ST_TILE(1) ST_TILE(2) ST_TILE(3)
        __builtin_amdgcn_s_setprio(0);
        __syncthreads();  // K frag reads done; P may overwrite KP

        // ---- yat score + mask + online softmax (per-lane row state) ----
        const bool diag = (kt == qt);
        float mm = -3e38f;
        YAT_TILE(0) YAT_TILE(1) YAT_TILE(2) YAT_TILE(3)
        mm = fmaxf(mm, __shfl_xor(mm, 16));
        mm = fmaxf(mm, __shfl_xor(mm, 32));
        const float mnew = fmaxf(mrun, mm);
        if (!__all(mm <= mrun)) {   // T13 defer-max (wave-uniform branch)
            const float al = __expf(mrun - mnew);
            const float a0 = __shfl(al, kq4 + 0, 16);
            const float a1 = __shfl(al, kq4 + 1, 16);
            const float a2 = __shfl(al, kq4 + 2, 16);
            const float a3 = __shfl(al, kq4 + 3, 16);
            ac0[0] *= a0; ac0[1] *= a1; ac0[2] *= a2; ac0[3] *= a3;
            ac1[0] *= a0; ac1[1] *= a1; ac1[2] *= a2; ac1[3] *= a3;
            ac2[0] *= a0; ac2[1] *= a1; ac2[2] *= a2; ac2[3] *= a3;
            ac3[0] *= a0; ac3[1] *= a1; ac3[2] *= a2; ac3[3] *= a3;
            lrun *= al;
        }
        mrun = mnew;
        float rs = 0.f;
        PEXP_TILE(0) PEXP_TILE(1) PEXP_TILE(2) PEXP_TILE(3)
        rs += __shfl_xor(rs, 16);
        rs += __shfl_xor(rs, 32);
        lrun += rs;
        __syncthreads();  // P writes visible

        // ---- O += P.V ----
        const bf16x8 ph0 = *(const bf16x8*)&KPh[pmrow + (kq << 3)];
        const bf16x8 ph1 = *(const bf16x8*)&KPh[pmrow + 32 + (kq << 3)];
        const bf16x8 pl0 = *(const bf16x8*)&KPl[pmrow + (kq << 3)];
        const bf16x8 pl1 = *(const bf16x8*)&KPl[pmrow + 32 + (kq << 3)];
        __builtin_amdgcn_s_setprio(1);
        PV_TILE(0) PV_TILE(1) PV_TILE(2) PV_TILE(3)
        __builtin_amdgcn_s_setprio(0);
    }

    const float i0 = 1.f / __shfl(lrun, kq4 + 0, 16);
    const float i1 = 1.f / __shfl(lrun, kq4 + 1, 16);
    const float i2 = 1.f / __shfl(lrun, kq4 + 2, 16);
    const float i3 = 1.f / __shfl(lrun, kq4 + 3, 16);
    const size_t obase = (size_t)(b * 1024 + (qt << 6) + wband + kq4) * 768 + h * 64 + lm;
    u16* oph = outh + obase;
    u16* opl = outl + obase;
    float rsum0 = 0.f, rsum1 = 0.f, rsum2 = 0.f, rsum3 = 0.f;
    #define STORE_E(j, r, iv) { \
        float ov = ac##j[r] * iv; \
        rsum##r += ov * ov; \
        u16 hh = bf16_rne(ov); \
        oph[(size_t)(r) * 768 + (j)*16] = hh; \
        opl[(size_t)(r) * 768 + (j)*16] = bf16_rne(ov - bf16_f(hh)); }
    #define STORE_T(j) { STORE_E(j,0,i0) STORE_E(j,1,i1) STORE_E(j,2,i2) STORE_E(j,3,i3) }
    STORE_T(0) STORE_T(1) STORE_T(2) STORE_T(3)
    #undef STORE_T
    #undef STORE_E
    const int arow = b * 1024 + (qt << 6) + wband + kq4;
    #define REDROW(r) { \
        float s = rsum##r; \
        s += __shfl_xor(s, 1, 16); \
        s += __shfl_xor(s, 2, 16); \
        s += __shfl_xor(s, 4, 16); \
        s += __shfl_xor(s, 8, 16); \
        if (lm == 0) atomicAdd(&an_g[arow + (r)], s); }
    REDROW(0) REDROW(1) REDROW(2) REDROW(3)
    #undef REDROW
}

extern "C" void kernel_launch(void* const* d_in, const int* in_sizes, int n_in,
                              void* d_out, int out_size, void* d_ws, size_t ws_size,
                              hipStream_t stream) {
    const float* x          = (const float*)d_in[0];
    // d_in[1] = mask (causal, known structure — unused)
    const float* W_attn     = (const float*)d_in[2];
    const float* b_attn     = (const float*)d_in[3];
    const float* alpha_attn = (const float*)d_in[4];
    const float* W_proj     = (const float*)d_in[5];
    const float* b_proj     = (const float*)d_in[6];
    const float* alpha_proj = (const float*)d_in[7];

    float* ws       = (float*)d_ws;
    u16*   qkvh     = (u16*)ws;              // [0, 4718592) f32-slots
    u16*   qkvl     = (u16*)(ws + 4718592);  // [4718592, 9437184)
    float* xn       = ws + 12582912;         // 4096
    float* an       = ws + 12587008;         // 4096 (zeroed by colnorm_reduce2; flash atomics)
    float* wn_attn  = ws + 12591104;         // 2304
    float* wn_proj  = ws + 12593408;         // 768
    float* qn       = ws + 12594176;         // 49152 (written by gemm1 epilogue)
    float* kn       = ws + 12643328;         // 49152

    float* cn_part_a = ws + 9437184;              // 16*2304
    float* cn_part_p = ws + 9437184 + 36864;      // 16*768
    u16* xh  = (u16*)(ws + 9437184);
    u16* xl  = (u16*)(ws + 11010048);
    u16* aoh = (u16*)(ws + 9437184);              // flash h/l output (xh/xl dead)
    u16* aol = (u16*)(ws + 11010048);
    u16* wth = (u16*)d_out;
    u16* wtl = (u16*)d_out + 1769472;
    u16* wph = (u16*)(ws + 3145728);              // inside qkvh region (dead post-flash)
    u16* wpl = (u16*)(ws + 3440640);

    colnorm_part2<<<dim3(48, 16), 256, 0, stream>>>(W_attn, W_proj, cn_part_a, cn_part_p);
    colnorm_reduce2<<<28, 256, 0, stream>>>(cn_part_a, cn_part_p, wn_attn, wn_proj, an);
    split_rownorm<<<1024, 256, 0, stream>>>(x, xh, xl, xn);
    split_wt_kernel<<<dim3(36, 12), 256, 0, stream>>>(W_attn, wth, wtl, 768, 2304);
    yat_gemm_mfma<1, 1><<<dim3(18, 32), 256, 0, stream>>>(
        xh, xl, wth, wtl, b_attn, xn, wn_attn, alpha_attn, 2304.f,
        nullptr, qkvh, qkvl, qn, kn, 2304, 768);
    yat_flash_mfma<<<768, 256, 0, stream>>>(qkvh, qkvl, qn, kn, aoh, aol, an);
    split_wt_kernel<<<dim3(12, 12), 256, 0, stream>>>(W_proj, wph, wpl, 768, 768);
    yat_gemm_mfma<0, 0><<<dim3(12, 64), 256, 0, stream>>>(
        aoh, aol, wph, wpl, b_proj, an, wn_proj, alpha_proj, 768.f,
        (float*)d_out, nullptr, nullptr, nullptr, nullptr, 768, 768);
}

// Round 12
// 231.589 us; speedup vs baseline: 1.0582x; 1.0582x over previous
//
#include <hip/hip_runtime.h>
#include <math.h>

#define EPS_YAT (1.0f/137.0f)

typedef unsigned short u16;
typedef unsigned int u32;
typedef __attribute__((ext_vector_type(8))) __bf16 bf16x8;
typedef __attribute__((ext_vector_type(4))) float f32x4;

__device__ __forceinline__ float4 ld4(const float* p) { return *(const float4*)p; }

__device__ __forceinline__ u16 bf16_rne(float f) {
    u32 u = __float_as_uint(f);
    u32 r = (u + 0x7fffu + ((u >> 16) & 1u)) >> 16;
    return (u16)r;
}
__device__ __forceinline__ float bf16_f(u16 h) {
    return __uint_as_float(((u32)h) << 16);
}

// async global->LDS DMA, 16B per lane. LDS dest is wave-uniform base + lane*16
// (m104); global src is per-lane (m173) -> swizzles go on the SOURCE address.
__device__ __forceinline__ void glds16(const u16* g, u16* s) {
    __builtin_amdgcn_global_load_lds(
        (const __attribute__((address_space(1))) void*)g,
        (__attribute__((address_space(3))) void*)s,
        16, 0, 0);
}

// ---- fused bf16 double-split + row norms of x (K=768): one read pass ----
__global__ void split_rownorm(const float* __restrict__ X, u16* __restrict__ Xh,
                              u16* __restrict__ Xl, float* __restrict__ rn) {
    int wave = threadIdx.x >> 6;
    int lane = threadIdx.x & 63;
    int row = blockIdx.x * 4 + wave;
    const float* xr = X + (size_t)row * 768;
    u16* xh = Xh + (size_t)row * 768;
    u16* xl = Xl + (size_t)row * 768;
    float s = 0.f;
    #pragma unroll
    for (int k = lane * 4; k < 768; k += 256) {
        float4 v = ld4(xr + k);
        s += v.x * v.x + v.y * v.y + v.z * v.z + v.w * v.w;
        u16 h0 = bf16_rne(v.x), h1 = bf16_rne(v.y), h2 = bf16_rne(v.z), h3 = bf16_rne(v.w);
        u16 l0 = bf16_rne(v.x - bf16_f(h0));
        u16 l1 = bf16_rne(v.y - bf16_f(h1));
        u16 l2 = bf16_rne(v.z - bf16_f(h2));
        u16 l3 = bf16_rne(v.w - bf16_f(h3));
        uint2 hp, lp;
        hp.x = (u32)h0 | ((u32)h1 << 16); hp.y = (u32)h2 | ((u32)h3 << 16);
        lp.x = (u32)l0 | ((u32)l1 << 16); lp.y = (u32)l2 | ((u32)l3 << 16);
        *(uint2*)(xh + k) = hp;
        *(uint2*)(xl + k) = lp;
    }
    for (int off = 32; off; off >>= 1) s += __shfl_down(s, off);
    if (lane == 0) rn[row] = s;
}

// ---- transpose + bf16 double-split + FUSED column norms:
// W [K][N] -> Th, Tl [N][K]; wn[n] += sum_k W[k][n]^2 (atomic, tile-local
// shuffle reduce first). Removes the separate colnorm pass (9.4MB re-read).
// wn must be zeroed before launch (hipMemsetAsync).
__global__ void split_wt_kernel(const float* __restrict__ W, u16* __restrict__ Th,
                                u16* __restrict__ Tl, float* __restrict__ wn,
                                int K, int N) {
    __shared__ float tile[64 * 68];
    const int tid = threadIdx.x;
    const int n0 = blockIdx.x << 6;
    const int k0 = blockIdx.y << 6;
    const int rr = tid >> 4;
    const int cc = (tid & 15) << 2;
    #pragma unroll
    for (int s = 0; s < 4; ++s) {
        int k_l = rr + s * 16;
        *(float4*)&tile[k_l * 68 + cc] = ld4(W + (size_t)(k0 + k_l) * N + n0 + cc);
    }
    __syncthreads();
    #pragma unroll
    for (int s = 0; s < 4; ++s) {
        int n_l = rr + s * 16;
        float a0 = tile[(cc + 0) * 68 + n_l];
        float a1 = tile[(cc + 1) * 68 + n_l];
        float a2 = tile[(cc + 2) * 68 + n_l];
        float a3 = tile[(cc + 3) * 68 + n_l];
        u16 h0 = bf16_rne(a0), h1 = bf16_rne(a1), h2 = bf16_rne(a2), h3 = bf16_rne(a3);
        u16 l0 = bf16_rne(a0 - bf16_f(h0));
        u16 l1 = bf16_rne(a1 - bf16_f(h1));
        u16 l2 = bf16_rne(a2 - bf16_f(h2));
        u16 l3 = bf16_rne(a3 - bf16_f(h3));
        uint2 hp, lp;
        hp.x = (u32)h0 | ((u32)h1 << 16); hp.y = (u32)h2 | ((u32)h3 << 16);
        lp.x = (u32)l0 | ((u32)l1 << 16); lp.y = (u32)l2 | ((u32)l3 << 16);
        size_t o = (size_t)(n0 + n_l) * K + k0 + cc;
        *(uint2*)(Th + o) = hp;
        *(uint2*)(Tl + o) = lp;
        // fused colnorm: 16 lanes (same rr, cc=0..60) hold this n's 64 k-vals
        float sq = a0 * a0 + a1 * a1 + a2 * a2 + a3 * a3;
        sq += __shfl_xor(sq, 1, 16);
        sq += __shfl_xor(sq, 2, 16);
        sq += __shfl_xor(sq, 4, 16);
        sq += __shfl_xor(sq, 8, 16);
        if ((tid & 15) == 0) atomicAdd(&wn[n0 + n_l], sq);
    }
}

// ---- yat GEMM (R10 config — best measured, 71.4us, 0 bank conflicts).
// BK=64, SINGLE-buffered LDS + gload_lds, m97 2-barrier loop, 3-bit chunk-XOR
// source swizzle (rule #21 both-sides involution). R11's counted-vmcnt graft
// regressed (m141 failure mode: order-pinning defeats compiler scheduling) —
// this 2-barrier structure is the plateau for this shape; do not re-pipeline.
template<int SPLIT, int BIG>
__global__ __launch_bounds__(256, BIG ? 2 : 4)
void yat_gemm_mfma(const u16* __restrict__ Ah, const u16* __restrict__ Al,
                   const u16* __restrict__ Bh, const u16* __restrict__ Bl,
                   const float* __restrict__ bias, const float* __restrict__ xn,
                   const float* __restrict__ wnc, const float* __restrict__ alphap,
                   const float Fdim, float* __restrict__ out,
                   u16* __restrict__ outh, u16* __restrict__ outl,
                   float* __restrict__ qn, float* __restrict__ kn,
                   const int N, const int K) {
    constexpr int TM = BIG ? 128 : 64;
    constexpr int TN = BIG ? 128 : 64;
    constexpr int JN = BIG ? 4 : 1;     // wave's n-subtiles (16 cols each)
    __shared__ __align__(16) u16 lds[(TM + TN) * 64 * 2];
    const int tid = threadIdx.x;
    // XCD swizzle (bijective: nwg 576 / 768, both %8==0)
    const int nwg = gridDim.x * gridDim.y;
    const int orig = blockIdx.y * gridDim.x + blockIdx.x;
    const int swz = (orig & 7) * (nwg >> 3) + (orig >> 3);
    const int m0 = (swz / gridDim.x) * TM;
    const int n0 = (swz % gridDim.x) * TN;
    const int w = tid >> 6;
    const int l = tid & 63;
    const int lm = l & 15;
    const int kq = l >> 4;
    const int kq4 = kq << 2;
    const int WM = BIG ? ((w >> 1) << 6) : 0;
    const int WN = BIG ? ((w & 1) << 6) : (w << 4);

    // staging: one glds16 covers 8 rows x 128B; lane l -> row +(l>>3); its
    // global 16B chunk is (l&7)^(l>>3)  [involution; row&7 == l>>3 since the
    // call's base row is a multiple of 8]
    const int lrow = l >> 3;
    const int swchunk = ((l & 7) ^ lrow) << 3;   // u16 offset of swizzled chunk

    u16* sAh = lds;
    u16* sAl = lds + TM * 64;
    u16* sBh = lds + 2 * TM * 64;
    u16* sBl = lds + 2 * TM * 64 + TN * 64;

    f32x4 acc[4][JN] = {};

    for (int k0 = 0; k0 < K; k0 += 64) {
        __syncthreads();                    // prior tile's frag reads done
        #pragma unroll
        for (int c = 0; c < TM / 32; ++c) {
            const int r0w = (TM / 4) * w + 8 * c;
            const size_t go = (size_t)(m0 + r0w + lrow) * K + k0 + swchunk;
            glds16(Ah + go, sAh + r0w * 64);
            glds16(Al + go, sAl + r0w * 64);
        }
        #pragma unroll
        for (int c = 0; c < TN / 32; ++c) {
            const int r0w = (TN / 4) * w + 8 * c;
            const size_t go = (size_t)(n0 + r0w + lrow) * K + k0 + swchunk;
            glds16(Bh + go, sBh + r0w * 64);
            glds16(Bl + go, sBl + r0w * 64);
        }
        __syncthreads();                    // implicit vmcnt(0): tile staged

        const int r7 = lm & 7;              // row&7 for this lane's frag rows
        #pragma unroll
        for (int kk = 0; kk < 2; ++kk) {
            const int ch = (((kk << 2) + kq) ^ r7) << 3;   // swizzled chunk
            bf16x8 fah[4], fal[4], fbh[JN], fbl[JN];
            #pragma unroll
            for (int i = 0; i < 4; ++i) {
                const int ra = (WM + i * 16 + lm) * 64 + ch;
                fah[i] = *(const bf16x8*)&sAh[ra];
                fal[i] = *(const bf16x8*)&sAl[ra];
            }
            #pragma unroll
            for (int j = 0; j < JN; ++j) {
                const int rb = (WN + j * 16 + lm) * 64 + ch;
                fbh[j] = *(const bf16x8*)&sBh[rb];
                fbl[j] = *(const bf16x8*)&sBl[rb];
            }
            #pragma unroll
            for (int i = 0; i < 4; ++i)
                #pragma unroll
                for (int j = 0; j < JN; ++j) {
                    f32x4 c = acc[i][j];
                    c = __builtin_amdgcn_mfma_f32_16x16x32_bf16(fah[i], fbh[j], c, 0, 0, 0);
                    c = __builtin_amdgcn_mfma_f32_16x16x32_bf16(fah[i], fbl[j], c, 0, 0, 0);
                    c = __builtin_amdgcn_mfma_f32_16x16x32_bf16(fal[i], fbh[j], c, 0, 0, 0);
                    acc[i][j] = c;
                }
        }
    }

    const float scale = powf(sqrtf(Fdim) / log1pf(Fdim), *alphap);
    float pp[4][4];
    #pragma unroll
    for (int i = 0; i < 4; ++i) {
        const int mbase = m0 + WM + i * 16 + kq4;
        #pragma unroll
        for (int r = 0; r < 4; ++r) pp[i][r] = 0.f;
        #pragma unroll
        for (int j = 0; j < JN; ++j) {
            const int n = n0 + WN + j * 16 + lm;
            const float w2 = wnc[n];
            const float bv = bias[n];
            #pragma unroll
            for (int r = 0; r < 4; ++r) {
                const int m = mbase + r;
                float d = acc[i][j][r];
                float den = xn[m] + w2 - 2.f * d + EPS_YAT;
                float v = (d * d / den + bv) * scale;
                if constexpr (SPLIT) {
                    u16 hh = bf16_rne(v);
                    outh[(size_t)m * N + n] = hh;
                    outl[(size_t)m * N + n] = bf16_rne(v - bf16_f(hh));
                    pp[i][r] += v * v;
                } else {
                    out[(size_t)m * N + n] = v;
                }
            }
        }
    }

    if constexpr (SPLIT) {
        // fused q/k norms: wave quadrant = one head's 64 cols x 64 rows.
        const int hcol = n0 + WN;
        if (hcol < 1536) {
            #pragma unroll
            for (int i = 0; i < 4; ++i)
                #pragma unroll
                for (int r = 0; r < 4; ++r) {
                    float s = pp[i][r];
                    s += __shfl_xor(s, 1, 16);
                    s += __shfl_xor(s, 2, 16);
                    s += __shfl_xor(s, 4, 16);
                    s += __shfl_xor(s, 8, 16);
                    if (lm == 0) {
                        const int m = m0 + WM + i * 16 + kq4 + r;
                        const int bb = m >> 10, t = m & 1023;
                        if (hcol < 768)
                            qn[(bb * 12 + (hcol >> 6)) * 1024 + t] = s;
                        else
                            kn[(bb * 12 + ((hcol - 768) >> 6)) * 1024 + t] = s;
                    }
                }
        }
    }
}

// ======================= MFMA flash attention (yat score) ====================
// (256,2): (256,4) capped VGPR at 64 and spilled (R5 lesson). T13 defer-max +
// fused an row-norm (atomicAdd per wave-row).
#define MFMA_B16(a, b, c) __builtin_amdgcn_mfma_f32_16x16x32_bf16(a, b, c, 0, 0, 0)

#define ST_TILE(j) { \
    const int kro = ((j)*16 + lm) * 72 + (kq << 3); \
    bf16x8 kh = *(const bf16x8*)&KPh[kro]; \
    bf16x8 kl = *(const bf16x8*)&KPl[kro]; \
    st##j = MFMA_B16(kh, qh0, st##j); \
    st##j = MFMA_B16(kl, qh0, st##j); \
    st##j = MFMA_B16(kh, ql0, st##j); \
    kh = *(const bf16x8*)&KPh[kro + 32]; \
    kl = *(const bf16x8*)&KPl[kro + 32]; \
    st##j = MFMA_B16(kh, qh1, st##j); \
    st##j = MFMA_B16(kl, qh1, st##j); \
    st##j = MFMA_B16(kh, ql1, st##j); \
}

#define YAT_EL(j, r) { \
    float sv = st##j[r] * 0.125f; \
    float den = qnm + kns[(j)*16 + kq4 + (r)] - 2.f * sv + EPS_YAT; \
    float v = sv * sv / den; \
    if (diag && ((j)*16 + kq4 + (r) > wband + lm)) v = -3e38f; \
    st##j[r] = v; mm = fmaxf(mm, v); }
#define YAT_TILE(j) YAT_EL(j,0) YAT_EL(j,1) YAT_EL(j,2) YAT_EL(j,3)

#define PEXP_TILE(j) { \
    float p0 = __expf(st##j[0] - mnew), p1 = __expf(st##j[1] - mnew); \
    float p2 = __expf(st##j[2] - mnew), p3 = __expf(st##j[3] - mnew); \
    rs += p0 + p1 + p2 + p3; \
    u16 h0 = bf16_rne(p0), h1 = bf16_rne(p1), h2 = bf16_rne(p2), h3 = bf16_rne(p3); \
    uint2 hp; hp.x = (u32)h0 | ((u32)h1 << 16); hp.y = (u32)h2 | ((u32)h3 << 16); \
    *(uint2*)&KPh[pmrow + (j)*16 + kq4] = hp; \
    u16 e0 = bf16_rne(p0 - bf16_f(h0)), e1 = bf16_rne(p1 - bf16_f(h1)); \
    u16 e2 = bf16_rne(p2 - bf16_f(h2)), e3 = bf16_rne(p3 - bf16_f(h3)); \
    uint2 lp; lp.x = (u32)e0 | ((u32)e1 << 16); lp.y = (u32)e2 | ((u32)e3 << 16); \
    *(uint2*)&KPl[pmrow + (j)*16 + kq4] = lp; }

#define PV_TILE(j) { \
    const int vro = ((j)*16 + lm) * 72 + vkq8; \
    bf16x8 vh = *(const bf16x8*)&Vth[vro]; \
    bf16x8 vl = *(const bf16x8*)&Vtl[vro]; \
    ac##j = MFMA_B16(ph0, vh, ac##j); \
    ac##j = MFMA_B16(pl0, vh, ac##j); \
    ac##j = MFMA_B16(ph0, vl, ac##j); \
    vh = *(const bf16x8*)&Vth[vro + 32]; \
    vl = *(const bf16x8*)&Vtl[vro + 32]; \
    ac##j = MFMA_B16(ph1, vh, ac##j); \
    ac##j = MFMA_B16(pl1, vh, ac##j); \
    ac##j = MFMA_B16(ph1, vl, ac##j); \
}

// transposed V staging from a pre-split uint2 (4 u16 along d), token column toks
#define WRVT(dst, v2, m) { \
    dst[(sj * 4 + 16 * (m) + 0) * 72 + toks] = (u16)((v2).x); \
    dst[(sj * 4 + 16 * (m) + 1) * 72 + toks] = (u16)((v2).x >> 16); \
    dst[(sj * 4 + 16 * (m) + 2) * 72 + toks] = (u16)((v2).y); \
    dst[(sj * 4 + 16 * (m) + 3) * 72 + toks] = (u16)((v2).y >> 16); }

__global__ __launch_bounds__(256, 2)
void yat_flash_mfma(const u16* __restrict__ qh_g, const u16* __restrict__ ql_g,
                    const float* __restrict__ qn, const float* __restrict__ kn,
                    u16* __restrict__ outh, u16* __restrict__ outl,
                    float* __restrict__ an_g) {
    __shared__ __align__(16) u16 KPh[64 * 72], KPl[64 * 72];  // Q prologue; K; P after St
    __shared__ __align__(16) u16 Vth[64 * 72], Vtl[64 * 72];  // V^T [d][tok^swz]
    __shared__ float kns[64];

    const int tid = threadIdx.x;
    const int L = blockIdx.x;         // 0..767
    const int u = L / 48;
    const int qt = (u & 1) ? (u >> 1) : (15 - (u >> 1));
    const int bh = L % 48;
    const int h = bh % 12, b = bh / 12;
    const int wave = tid >> 6;
    const int lane = tid & 63;
    const int lm = lane & 15;
    const int kq = lane >> 4;
    const int kq4 = kq << 2;
    const int wband = wave << 4;
    const int sr = tid >> 2;          // staging token row 0..63
    const int sj = tid & 3;           // staging d-group
    const int toks = sr ^ (sj << 3);  // swizzled Vt column
    const int vkq8 = (kq ^ (lm >> 2)) << 3;
    const size_t base = (size_t)(b * 1024) * 2304 + h * 64;

    // ---- stage Q through KPh/KPl (only needed until frag reads) ----
    {
        const size_t qoff = base + (size_t)((qt << 6) + sr) * 2304 + sj * 16;
        *(uint4*)&KPh[sr * 72 + sj * 16]     = *(const uint4*)(qh_g + qoff);
        *(uint4*)&KPh[sr * 72 + sj * 16 + 8] = *(const uint4*)(qh_g + qoff + 8);
        *(uint4*)&KPl[sr * 72 + sj * 16]     = *(const uint4*)(ql_g + qoff);
        *(uint4*)&KPl[sr * 72 + sj * 16 + 8] = *(const uint4*)(ql_g + qoff + 8);
    }
    const float qnm = qn[bh * 1024 + (qt << 6) + wband + lm];

    // prefetch kt=0 K/V (pre-split u16) into registers
    const size_t r0 = base + (size_t)sr * 2304;
    uint4 kh0 = *(const uint4*)(qh_g + r0 + 768 + sj * 16);
    uint4 kh1 = *(const uint4*)(qh_g + r0 + 768 + sj * 16 + 8);
    uint4 kl0 = *(const uint4*)(ql_g + r0 + 768 + sj * 16);
    uint4 kl1 = *(const uint4*)(ql_g + r0 + 768 + sj * 16 + 8);
    uint2 vh0 = *(const uint2*)(qh_g + r0 + 1536 + sj * 4);
    uint2 vh1 = *(const uint2*)(qh_g + r0 + 1536 + sj * 4 + 16);
    uint2 vh2 = *(const uint2*)(qh_g + r0 + 1536 + sj * 4 + 32);
    uint2 vh3 = *(const uint2*)(qh_g + r0 + 1536 + sj * 4 + 48);
    uint2 vl0 = *(const uint2*)(ql_g + r0 + 1536 + sj * 4);
    uint2 vl1 = *(const uint2*)(ql_g + r0 + 1536 + sj * 4 + 16);
    uint2 vl2 = *(const uint2*)(ql_g + r0 + 1536 + sj * 4 + 32);
    uint2 vl3 = *(const uint2*)(ql_g + r0 + 1536 + sj * 4 + 48);
    float knS = (tid < 64) ? kn[bh * 1024 + tid] : 0.f;

    __syncthreads();  // Q staged

    // loop-invariant Q fragments (B-operand: Q^T via row-major Q)
    const int qrow = (wband + lm) * 72;
    const bf16x8 qh0 = *(const bf16x8*)&KPh[qrow + (kq << 3)];
    const bf16x8 qh1 = *(const bf16x8*)&KPh[qrow + 32 + (kq << 3)];
    const bf16x8 ql0 = *(const bf16x8*)&KPl[qrow + (kq << 3)];
    const bf16x8 ql1 = *(const bf16x8*)&KPl[qrow + 32 + (kq << 3)];

    f32x4 ac0 = {}, ac1 = {}, ac2 = {}, ac3 = {};
    float mrun = -3e38f, lrun = 0.f;
    const int pmrow = (wband + lm) * 72;

    for (int kt = 0; kt <= qt; ++kt) {
        __syncthreads();  // Q frag reads (iter0) / prior PV reads done
        *(uint4*)&KPh[sr * 72 + sj * 16]     = kh0;
        *(uint4*)&KPh[sr * 72 + sj * 16 + 8] = kh1;
        *(uint4*)&KPl[sr * 72 + sj * 16]     = kl0;
        *(uint4*)&KPl[sr * 72 + sj * 16 + 8] = kl1;
        WRVT(Vth, vh0, 0) WRVT(Vth, vh1, 1) WRVT(Vth, vh2, 2) WRVT(Vth, vh3, 3)
        WRVT(Vtl, vl0, 0) WRVT(Vtl, vl1, 1) WRVT(Vtl, vl2, 2) WRVT(Vtl, vl3, 3)
        if (tid < 64) kns[tid] = knS;
        __syncthreads();

        if (kt < qt) {  // prefetch kt+1 (block-uniform)
            const size_t r = base + (size_t)(((kt + 1) << 6) + sr) * 2304;
            kh0 = *(const uint4*)(qh_g + r + 768 + sj * 16);
            kh1 = *(const uint4*)(qh_g + r + 768 + sj * 16 + 8);
            kl0 = *(const uint4*)(ql_g + r + 768 + sj * 16);
            kl1 = *(const uint4*)(ql_g + r + 768 + sj * 16 + 8);
            vh0 = *(const uint2*)(qh_g + r + 1536 + sj * 4);
            vh1 = *(const uint2*)(qh_g + r + 1536 + sj * 4 + 16);
            vh2 = *(const uint2*)(qh_g + r + 1536 + sj * 4 + 32);
            vh3 = *(const uint2*)(qh_g + r + 1536 + sj * 4 + 48);
            vl0 = *(const uint2*)(ql_g + r + 1536 + sj * 4);
            vl1 = *(const uint2*)(ql_g + r + 1536 + sj * 4 + 16);
            vl2 = *(const uint2*)(ql_g + r + 1536 + sj * 4 + 32);
            vl3 = *(const uint2*)(ql_g + r + 1536 + sj * 4 + 48);
            if (tid < 64) knS = kn[bh * 1024 + ((kt + 1) << 6) + tid];
        }

        // ---- St = K.Q^T (each lane: one m = wband+lm, n = j*16+kq*4+r) ----
        f32x4 st0 = {}, st1 = {}, st2 = {}, st3 = {};
        __builtin_amdgcn_s_setprio(1);
        ST_TILE(0) ST_TILE(1) ST_TILE(2) ST_TILE(3)
        __builtin_amdgcn_s_setprio(0);
        __syncthreads();  // K frag reads done; P may overwrite KP

        // ---- yat score + mask + online softmax (per-lane row state) ----
        const bool diag = (kt == qt);
        float mm = -3e38f;
        YAT_TILE(0) YAT_TILE(1) YAT_TILE(2) YAT_TILE(3)
        mm = fmaxf(mm, __shfl_xor(mm, 16));
        mm = fmaxf(mm, __shfl_xor(mm, 32));
        const float mnew = fmaxf(mrun, mm);
        if (!__all(mm <= mrun)) {   // T13 defer-max (wave-uniform branch)
            const float al = __expf(mrun - mnew);
            const float a0 = __shfl(al, kq4 + 0, 16);
            const float a1 = __shfl(al, kq4 + 1, 16);
            const float a2 = __shfl(al, kq4 + 2, 16);
            const float a3 = __shfl(al, kq4 + 3, 16);
            ac0[0] *= a0; ac0[1] *= a1; ac0[2] *= a2; ac0[3] *= a3;
            ac1[0] *= a0; ac1[1] *= a1; ac1[2] *= a2; ac1[3] *= a3;
            ac2[0] *= a0; ac2[1] *= a1; ac2[2] *= a2; ac2[3] *= a3;
            ac3[0] *= a0; ac3[1] *= a1; ac3[2] *= a2; ac3[3] *= a3;
            lrun *= al;
        }
        mrun = mnew;
        float rs = 0.f;
        PEXP_TILE(0) PEXP_TILE(1) PEXP_TILE(2) PEXP_TILE(3)
        rs += __shfl_xor(rs, 16);
        rs += __shfl_xor(rs, 32);
        lrun += rs;
        __syncthreads();  // P writes visible

        // ---- O += P.V ----
        const bf16x8 ph0 = *(const bf16x8*)&KPh[pmrow + (kq << 3)];
        const bf16x8 ph1 = *(const bf16x8*)&KPh[pmrow + 32 + (kq << 3)];
        const bf16x8 pl0 = *(const bf16x8*)&KPl[pmrow + (kq << 3)];
        const bf16x8 pl1 = *(const bf16x8*)&KPl[pmrow + 32 + (kq << 3)];
        __builtin_amdgcn_s_setprio(1);
        PV_TILE(0) PV_TILE(1) PV_TILE(2) PV_TILE(3)
        __builtin_amdgcn_s_setprio(0);
    }

    const float i0 = 1.f / __shfl(lrun, kq4 + 0, 16);
    const float i1 = 1.f / __shfl(lrun, kq4 + 1, 16);
    const float i2 = 1.f / __shfl(lrun, kq4 + 2, 16);
    const float i3 = 1.f / __shfl(lrun, kq4 + 3, 16);
    const size_t obase = (size_t)(b * 1024 + (qt << 6) + wband + kq4) * 768 + h * 64 + lm;
    u16* oph = outh + obase;
    u16* opl = outl + obase;
    float rsum0 = 0.f, rsum1 = 0.f, rsum2 = 0.f, rsum3 = 0.f;
    #define STORE_E(j, r, iv) { \
        float ov = ac##j[r] * iv; \
        rsum##r += ov * ov; \
        u16 hh = bf16_rne(ov); \
        oph[(size_t)(r) * 768 + (j)*16] = hh; \
        opl[(size_t)(r) * 768 + (j)*16] = bf16_rne(ov - bf16_f(hh)); }
    #define STORE_T(j) { STORE_E(j,0,i0) STORE_E(j,1,i1) STORE_E(j,2,i2) STORE_E(j,3,i3) }
    STORE_T(0) STORE_T(1) STORE_T(2) STORE_T(3)
    #undef STORE_T
    #undef STORE_E
    const int arow = b * 1024 + (qt << 6) + wband + kq4;
    #define REDROW(r) { \
        float s = rsum##r; \
        s += __shfl_xor(s, 1, 16); \
        s += __shfl_xor(s, 2, 16); \
        s += __shfl_xor(s, 4, 16); \
        s += __shfl_xor(s, 8, 16); \
        if (lm == 0) atomicAdd(&an_g[arow + (r)], s); }
    REDROW(0) REDROW(1) REDROW(2) REDROW(3)
    #undef REDROW
}

extern "C" void kernel_launch(void* const* d_in, const int* in_sizes, int n_in,
                              void* d_out, int out_size, void* d_ws, size_t ws_size,
                              hipStream_t stream) {
    const float* x          = (const float*)d_in[0];
    // d_in[1] = mask (causal, known structure — unused)
    const float* W_attn     = (const float*)d_in[2];
    const float* b_attn     = (const float*)d_in[3];
    const float* alpha_attn = (const float*)d_in[4];
    const float* W_proj     = (const float*)d_in[5];
    const float* b_proj     = (const float*)d_in[6];
    const float* alpha_proj = (const float*)d_in[7];

    float* ws       = (float*)d_ws;
    u16*   qkvh     = (u16*)ws;              // [0, 4718592) f32-slots
    u16*   qkvl     = (u16*)(ws + 4718592);  // [4718592, 9437184)
    float* xn       = ws + 12582912;         // 4096
    float* an       = ws + 12587008;         // 4096 (memset-zeroed; flash atomics)
    float* wn_attn  = ws + 12591104;         // 2304 (memset-zeroed; split_wt atomics)
    float* wn_proj  = ws + 12593408;         // 768  (memset-zeroed; split_wt atomics)
    float* qn       = ws + 12594176;         // 49152 (written by gemm1 epilogue)
    float* kn       = ws + 12643328;         // 49152

    u16* xh  = (u16*)(ws + 9437184);
    u16* xl  = (u16*)(ws + 11010048);
    u16* aoh = (u16*)(ws + 9437184);              // flash h/l output (xh/xl dead)
    u16* aol = (u16*)(ws + 11010048);
    u16* wth = (u16*)d_out;
    u16* wtl = (u16*)d_out + 1769472;
    u16* wph = (u16*)(ws + 3145728);              // inside qkvh region (dead post-flash)
    u16* wpl = (u16*)(ws + 3440640);

    // zero an + wn_attn + wn_proj (contiguous 7168 floats) for atomic accum
    hipMemsetAsync((void*)an, 0, 7168 * sizeof(float), stream);
    split_rownorm<<<1024, 256, 0, stream>>>(x, xh, xl, xn);
    split_wt_kernel<<<dim3(36, 12), 256, 0, stream>>>(W_attn, wth, wtl, wn_attn, 768, 2304);
    yat_gemm_mfma<1, 1><<<dim3(18, 32), 256, 0, stream>>>(
        xh, xl, wth, wtl, b_attn, xn, wn_attn, alpha_attn, 2304.f,
        nullptr, qkvh, qkvl, qn, kn, 2304, 768);
    yat_flash_mfma<<<768, 256, 0, stream>>>(qkvh, qkvl, qn, kn, aoh, aol, an);
    split_wt_kernel<<<dim3(12, 12), 256, 0, stream>>>(W_proj, wph, wpl, wn_proj, 768, 768);
    yat_gemm_mfma<0, 0><<<dim3(12, 64), 256, 0, stream>>>(
        aoh, aol, wph, wpl, b_proj, an, wn_proj, alpha_proj, 768.f,
        (float*)d_out, nullptr, nullptr, nullptr, nullptr, 768, 768);
}